// Round 5
// baseline (699.149 us; speedup 1.0000x reference)
//
#include <hip/hip_runtime.h>
#include <math.h>

#define D 256
#define K 1024
#define NROWS 65536
#define MARGIN 0.125f
#define CAND_MAX 256

typedef __bf16 bf16x8 __attribute__((ext_vector_type(8)));
typedef float f32x16 __attribute__((ext_vector_type(16)));

// async global->LDS, 16B per lane; lds base must be wave-uniform, lane i lands at base + i*16
#define GL2LDS16(g, l) __builtin_amdgcn_global_load_lds( \
    (const __attribute__((address_space(1))) char*)(const void*)(g), \
    (__attribute__((address_space(3))) char*)(void*)(l), 16, 0, 0)

__device__ inline float wave_sum_f(float v){
  #pragma unroll
  for (int off = 32; off; off >>= 1) v += __shfl_down(v, off);
  return v;
}
__device__ inline double wave_sum_d(double v){
  #pragma unroll
  for (int off = 32; off; off >>= 1) v += __shfl_down(v, off);
  return v;
}

// ---------------- pass 0a: split x into bf16 hi/lo + row norms ----------------
__global__ __launch_bounds__(256) void split_rows(const float* __restrict__ x,
                                                  __bf16* __restrict__ xh,
                                                  __bf16* __restrict__ xl,
                                                  float* __restrict__ xnorm){
  const int t = threadIdx.x;
  const int w = t >> 6, lane = t & 63;
  const size_t row = (size_t)blockIdx.x * 4 + w;
  const float4 v = *(const float4*)(x + row * D + lane * 4);
  float s = v.x*v.x + v.y*v.y + v.z*v.z + v.w*v.w;
  s = wave_sum_f(s);
  union { __bf16 b[4]; short4 s4; } uh, ul;
  const float vv[4] = {v.x, v.y, v.z, v.w};
  #pragma unroll
  for (int j = 0; j < 4; j++){
    __bf16 h = (__bf16)vv[j];
    uh.b[j] = h;
    ul.b[j] = (__bf16)(vv[j] - (float)h);
  }
  *(short4*)(xh + row * D + lane * 4) = uh.s4;
  *(short4*)(xl + row * D + lane * 4) = ul.s4;
  if (lane == 0) xnorm[row] = s;
}

// ---------------- pass 0b: codebook transpose (fp32 + bf16 hi/lo) + col norms ----------------
__global__ __launch_bounds__(256) void prep_codebook(const float* __restrict__ cb,
                                                     float* __restrict__ cT,
                                                     __bf16* __restrict__ ch,
                                                     __bf16* __restrict__ cl,
                                                     float* __restrict__ cnorm){
  const int k = blockIdx.x;
  const int t = threadIdx.x;
  const int w = t >> 6, lane = t & 63;
  float v = cb[(size_t)t * K + k];
  cT[(size_t)k * D + t] = v;
  __bf16 h = (__bf16)v;
  ch[(size_t)k * D + t] = h;
  cl[(size_t)k * D + t] = (__bf16)(v - (float)h);
  float s = wave_sum_f(v * v);
  __shared__ float red[4];
  if (lane == 0) red[w] = s;
  __syncthreads();
  if (t == 0) cnorm[k] = red[0] + red[1] + red[2] + red[3];
}

// ---------------- fused pass 1: 32-row x 1024-code block, quarter-phase staging -----------
// 512 threads = 8 waves, 2 blocks/CU (LDS ~38KB, VGPR <=128 via launch_bounds(512,4)).
// Wave w computes sub-tile s at codes [s*256 + w*32, +32) so every wave works every phase.
// Phase p = k0*4+q stages only the next 256-code x 16-k slice (16KB, 2 loads/wave) -> small
// per-barrier vmcnt drain, hidden by the co-resident block's compute (m114 overlap).
__global__ __launch_bounds__(512, 4) void vq_fused(
    const __bf16* __restrict__ xh, const __bf16* __restrict__ xl,
    const __bf16* __restrict__ ch, const __bf16* __restrict__ cl,
    const float* __restrict__ cnorm, const float* __restrict__ xnorm,
    float* __restrict__ soft, int* __restrict__ cand_cnt, int* __restrict__ cand_buf)
{
  __shared__ __bf16 Bh[2][256 * 16];   // 8 KB each -> 16 KB
  __shared__ __bf16 Bl[2][256 * 16];   // 16 KB
  __shared__ __bf16 Ah[2][32 * 16];    // 2 KB
  __shared__ __bf16 Al[2][32 * 16];    // 2 KB
  __shared__ float xns[32];
  __shared__ float redmax[8][32];      // 1 KB
  __shared__ float redsum[8][32];      // 1 KB
  __shared__ float rowilim[32];
  __shared__ float rowrs[32];
  __shared__ int   lcand[CAND_MAX];    // 1 KB
  __shared__ int   lcnt;

  const int t = threadIdx.x, w = t >> 6, lane = t & 63;
  const int col = lane & 31, hi = lane >> 5;
  const size_t base = (size_t)blockIdx.x * 32;

  if (t < 32) xns[t] = xnorm[base + t];
  if (t == 0) lcnt = 0;

  // stage one 256-code x 16-k slice (phase q of k-step k0): 2 loads per wave
  auto stageB = [&](int buf, int k0, int q){
    const size_t go = (size_t)(q * 256 + w * 32 + (lane >> 1)) * D + k0 * 16 + (lane & 1) * 8;
    GL2LDS16(ch + go, &Bh[buf][w * 512]);
    GL2LDS16(cl + go, &Bl[buf][w * 512]);
  };
  // stage A (32 rows x 16 k, hi+lo): waves 0,1 only, 1 load each
  auto stageA = [&](int buf, int k0){
    if (w < 2){
      const size_t go = (base + (lane >> 1)) * (size_t)D + k0 * 16 + (lane & 1) * 8;
      if (w == 0) GL2LDS16(xh + go, &Ah[buf][0]);
      else        GL2LDS16(xl + go, &Al[buf][0]);
    }
  };

  f32x16 acc[4];
  #pragma unroll
  for (int s = 0; s < 4; s++)
    #pragma unroll
    for (int j = 0; j < 16; j++) acc[s][j] = 0.f;

  // prologue: phase 0 + its A, phase 1
  stageA(0, 0);
  stageB(0, 0, 0);
  stageB(1, 0, 1);

  bf16x8 a_h, a_l;
  for (int k0 = 0; k0 < 16; k0++){
    #pragma unroll
    for (int q = 0; q < 4; q++){
      const int p = k0 * 4 + q;
      __syncthreads();                      // drains vmcnt: phase-p slice landed; buf[(p+1)&1] free
      const int pn = p + 1;
      if (pn < 64) stageB(pn & 1, pn >> 2, pn & 3);
      if (q == 0){
        if (k0 + 1 < 16) stageA((k0 + 1) & 1, k0 + 1);
        a_h = *(const bf16x8*)&Ah[k0 & 1][col * 16 + hi * 8];
        a_l = *(const bf16x8*)&Al[k0 & 1][col * 16 + hi * 8];
      }
      const int bb = p & 1;
      const bf16x8 b_h = *(const bf16x8*)&Bh[bb][(w * 32 + col) * 16 + hi * 8];
      const bf16x8 b_l = *(const bf16x8*)&Bl[bb][(w * 32 + col) * 16 + hi * 8];
      acc[q] = __builtin_amdgcn_mfma_f32_32x32x16_bf16(a_h, b_h, acc[q], 0, 0, 0);
      acc[q] = __builtin_amdgcn_mfma_f32_32x32x16_bf16(a_h, b_l, acc[q], 0, 0, 0);
      acc[q] = __builtin_amdgcn_mfma_f32_32x32x16_bf16(a_l, b_h, acc[q], 0, 0, 0);
    }
  }

  // ---- epilogue: sim -> dist -> iv in place; per-row {max iv, sum iv^2} ----
  float cn[4];
  #pragma unroll
  for (int s = 0; s < 4; s++) cn[s] = cnorm[s * 256 + w * 32 + col];

  float pmax[16], psum[16];
  #pragma unroll
  for (int r = 0; r < 16; r++){
    const int row = (r & 3) + 8 * (r >> 2) + 4 * hi;   // m74/m101-verified 32x32 C layout
    const float xn = xns[row];
    float mx = 0.f, sm = 0.f;
    #pragma unroll
    for (int s = 0; s < 4; s++){
      const float d = xn + cn[s] - 2.0f * acc[s][r];
      const float iv = 1.0f / d;
      acc[s][r] = iv;
      mx = fmaxf(mx, iv);
      sm += iv * iv;
    }
    pmax[r] = mx; psum[r] = sm;
  }
  #pragma unroll
  for (int mask = 1; mask <= 16; mask <<= 1)
    #pragma unroll
    for (int r = 0; r < 16; r++){
      pmax[r] = fmaxf(pmax[r], __shfl_xor(pmax[r], mask));
      psum[r] += __shfl_xor(psum[r], mask);
    }
  if (col == 0){
    #pragma unroll
    for (int r = 0; r < 16; r++){
      const int row = (r & 3) + 8 * (r >> 2) + 4 * hi;
      redmax[w][row] = pmax[r];
      redsum[w][row] = psum[r];
    }
  }
  __syncthreads();
  if (t < 32){
    float mx = 0.f, sm = 0.f;
    #pragma unroll
    for (int ww = 0; ww < 8; ww++){
      mx = fmaxf(mx, redmax[ww][t]);
      sm += redsum[ww][t];
    }
    rowilim[t] = 1.0f / (1.0f / mx + MARGIN);   // iv >= ilim  <=>  d <= dmin + MARGIN
    rowrs[t]   = 1.0f / sm;
  }
  __syncthreads();

  // ---- write soft directly (nt stores) + collect candidates ----
  #pragma unroll
  for (int r = 0; r < 16; r++){
    const int row = (r & 3) + 8 * (r >> 2) + 4 * hi;
    const float ilim = rowilim[row], rs = rowrs[row];
    const size_t rowoff = (base + row) * (size_t)K + w * 32 + col;
    #pragma unroll
    for (int s = 0; s < 4; s++){
      const float iv = acc[s][r];
      __builtin_nontemporal_store(iv * iv * rs, &soft[rowoff + s * 256]);
      if (iv >= ilim){
        const int p = atomicAdd(&lcnt, 1);
        if (p < CAND_MAX) lcand[p] = (row << 10) | (s * 256 + w * 32 + col);
      }
    }
  }
  __syncthreads();
  const int n = min(lcnt, CAND_MAX);
  if (t == 0) cand_cnt[blockIdx.x] = n;
  for (int i = t; i < n; i += 512)
    cand_buf[(size_t)blockIdx.x * CAND_MAX + i] = lcand[i];
}

// ---------------- pass 2 (lite): fp64-refined argmin among candidates + quantize + loss -------
__global__ __launch_bounds__(256) void vq_refine(
    const float* __restrict__ x, const float* __restrict__ cT,
    const int* __restrict__ cand_cnt, const int* __restrict__ cand_buf,
    float* __restrict__ q_out, double* __restrict__ loss_acc)
{
  __shared__ int    lcand[CAND_MAX];
  __shared__ double cand_d[CAND_MAX];
  __shared__ int    rowbest[32];
  __shared__ double bestd[32];

  const int t = threadIdx.x, w = t >> 6, lane = t & 63;
  const size_t base = (size_t)blockIdx.x * 32;
  const int n = cand_cnt[blockIdx.x];
  for (int i = t; i < n; i += 256)
    lcand[i] = cand_buf[(size_t)blockIdx.x * CAND_MAX + i];
  __syncthreads();

  for (int c = w; c < n; c += 4){
    const int rk = lcand[c], r = rk >> 10, k = rk & 1023;
    const float4 xv = *(const float4*)(x  + (base + r) * (size_t)D + lane * 4);
    const float4 cv = *(const float4*)(cT + (size_t)k * D + lane * 4);
    double s = 0.0, dx;
    dx = (double)xv.x - (double)cv.x; s += dx * dx;
    dx = (double)xv.y - (double)cv.y; s += dx * dx;
    dx = (double)xv.z - (double)cv.z; s += dx * dx;
    dx = (double)xv.w - (double)cv.w; s += dx * dx;
    s = wave_sum_d(s);
    if (lane == 0) cand_d[c] = s;
  }
  __syncthreads();

  if (t < 32){
    double best = 1e300; int bi = 1 << 20;
    for (int c = 0; c < n; c++){
      const int rk = lcand[c];
      if ((rk >> 10) == t){
        const double dd = cand_d[c];
        const int k = rk & 1023;
        if (dd < best || (dd == best && k < bi)){ best = dd; bi = k; }
      }
    }
    rowbest[t] = (bi < K) ? bi : 0;   // OOB safety; impossible in practice
    bestd[t] = best;
  }
  __syncthreads();

  #pragma unroll 4
  for (int r = 0; r < 32; r++){
    const float q = cT[(size_t)rowbest[r] * D + t];
    __builtin_nontemporal_store(q, &q_out[(base + r) * (size_t)D + t]);
  }

  if (t == 0){
    double s = 0.0;
    #pragma unroll
    for (int r = 0; r < 32; r++) s += bestd[r];
    atomicAdd(loss_acc, s);
  }
}

// ---------------- finalize loss ----------------
__global__ void finalize_loss(const double* __restrict__ acc, float* __restrict__ out_loss){
  out_loss[0] = (float)(1.25 * acc[0] / (double)((size_t)NROWS * D));
}

extern "C" void kernel_launch(void* const* d_in, const int* in_sizes, int n_in,
                              void* d_out, int out_size, void* d_ws, size_t ws_size,
                              hipStream_t stream) {
  const float* x  = (const float*)d_in[0];   // [65536,256]
  const float* cb = (const float*)d_in[1];   // [256,1024]

  float* out      = (float*)d_out;
  float* q_out    = out;                                          // 16777216
  float* soft     = out + (size_t)NROWS * D;                      // 67108864
  float* loss_out = out + (size_t)NROWS * D + (size_t)NROWS * K;  // 1

  char* ws = (char*)d_ws;
  double* acc      = (double*)ws;                 // @0        (8 B)
  float*  cnorm    = (float*)(ws + 4096);         // 4 KB
  int*    cand_cnt = (int*)(ws + 16384);          // 8 KB
  float*  xnorm    = (float*)(ws + 262144);       // 256 KB
  int*    cand_buf = (int*)(ws + 524288);         // 2 MB region
  float*  cT       = (float*)(ws + 2621440);      // 1 MB
  __bf16* ch       = (__bf16*)(ws + 3670016);     // 512 KB
  __bf16* cl       = (__bf16*)(ws + 4194304);     // 512 KB
  __bf16* xh       = (__bf16*)(ws + 4718592);     // 32 MB
  __bf16* xl       = (__bf16*)(ws + 38273024);    // 32 MB  (total ~68.5 MB)

  hipMemsetAsync(acc, 0, sizeof(double), stream);
  split_rows<<<NROWS / 4, 256, 0, stream>>>(x, xh, xl, xnorm);
  prep_codebook<<<K, 256, 0, stream>>>(cb, cT, ch, cl, cnorm);
  vq_fused<<<NROWS / 32, 512, 0, stream>>>(xh, xl, ch, cl, cnorm, xnorm, soft, cand_cnt, cand_buf);
  vq_refine<<<NROWS / 32, 256, 0, stream>>>(x, cT, cand_cnt, cand_buf, q_out, acc);
  finalize_loss<<<1, 1, 0, stream>>>(acc, loss_out);
}

// Round 6
// 574.274 us; speedup vs baseline: 1.2174x; 1.2174x over previous
//
#include <hip/hip_runtime.h>
#include <math.h>

#define D 256
#define K 1024
#define NROWS 65536
#define MARGIN 0.75f
#define CAND_MAX 512

typedef __bf16 bf16x8 __attribute__((ext_vector_type(8)));
typedef float f32x16 __attribute__((ext_vector_type(16)));

// async global->LDS, 16B per lane; lds base must be wave-uniform, lane i lands at base + i*16
#define GL2LDS16(g, l) __builtin_amdgcn_global_load_lds( \
    (const __attribute__((address_space(1))) char*)(const void*)(g), \
    (__attribute__((address_space(3))) char*)(void*)(l), 16, 0, 0)

__device__ inline float wave_sum_f(float v){
  #pragma unroll
  for (int off = 32; off; off >>= 1) v += __shfl_down(v, off);
  return v;
}
__device__ inline double wave_sum_d(double v){
  #pragma unroll
  for (int off = 32; off; off >>= 1) v += __shfl_down(v, off);
  return v;
}

// ---------------- pass 0a: x -> bf16 + fp32 row norms (norms from ORIGINAL fp32 x) ----------
__global__ __launch_bounds__(256) void split_rows(const float* __restrict__ x,
                                                  __bf16* __restrict__ xh,
                                                  float* __restrict__ xnorm){
  const int t = threadIdx.x;
  const int w = t >> 6, lane = t & 63;
  const size_t row = (size_t)blockIdx.x * 4 + w;
  const float4 v = *(const float4*)(x + row * D + lane * 4);
  float s = v.x*v.x + v.y*v.y + v.z*v.z + v.w*v.w;
  s = wave_sum_f(s);
  union { __bf16 b[4]; short4 s4; } uh;
  uh.b[0] = (__bf16)v.x; uh.b[1] = (__bf16)v.y;
  uh.b[2] = (__bf16)v.z; uh.b[3] = (__bf16)v.w;
  *(short4*)(xh + row * D + lane * 4) = uh.s4;
  if (lane == 0) xnorm[row] = s;
}

// ---------------- pass 0b: codebook transpose (fp32 + bf16) + fp32 col norms ----------------
__global__ __launch_bounds__(256) void prep_codebook(const float* __restrict__ cb,
                                                     float* __restrict__ cT,
                                                     __bf16* __restrict__ ch,
                                                     float* __restrict__ cnorm){
  const int k = blockIdx.x;
  const int t = threadIdx.x;
  const int w = t >> 6, lane = t & 63;
  float v = cb[(size_t)t * K + k];
  cT[(size_t)k * D + t] = v;
  ch[(size_t)k * D + t] = (__bf16)v;
  float s = wave_sum_f(v * v);
  __shared__ float red[4];
  if (lane == 0) red[w] = s;
  __syncthreads();
  if (t == 0) cnorm[k] = red[0] + red[1] + red[2] + red[3];
}

// ---------------- fused pass 1: 32-row x 1024-code block, pure-bf16 GEMM ------------------
// 512 threads = 8 waves, 2 blocks/CU. dist error ~0.05 abs (on dist~341) -> soft err ~3e-7;
// argmin is refined in fp64 over candidates within MARGIN=0.75 (~10 sigma of the bf16 error).
// Half-B phases: 32 phases, each stages 512 codes x 16 k (16 KB, 2 loads/wave) + 2 MFMA/wave.
__global__ __launch_bounds__(512, 4) void vq_fused(
    const __bf16* __restrict__ xh, const __bf16* __restrict__ ch,
    const float* __restrict__ cnorm, const float* __restrict__ xnorm,
    float* __restrict__ soft, int* __restrict__ cand_cnt, int* __restrict__ cand_buf)
{
  __shared__ __bf16 B[2][512 * 16];    // 16 KB each -> 32 KB
  __shared__ __bf16 A[2][32 * 16];     // 1 KB each -> 2 KB
  __shared__ float xns[32];
  __shared__ float redmax[8][32];      // 1 KB
  __shared__ float redsum[8][32];      // 1 KB
  __shared__ float rowilim[32];
  __shared__ float rowrs[32];
  __shared__ int   lcand[CAND_MAX];    // 2 KB
  __shared__ int   lcnt;

  const int t = threadIdx.x, w = t >> 6, lane = t & 63;
  const int col = lane & 31, hi = lane >> 5;
  const size_t base = (size_t)blockIdx.x * 32;

  if (t < 32) xns[t] = xnorm[base + t];
  if (t == 0) lcnt = 0;

  // stage one 512-code x 16-k slice (phase q of k-step k0): 2 loads per wave
  auto stageB = [&](int buf, int k0, int q){
    #pragma unroll
    for (int i = 0; i < 2; i++){
      const size_t go = (size_t)(q * 512 + w * 64 + i * 32 + (lane >> 1)) * D
                        + k0 * 16 + (lane & 1) * 8;
      GL2LDS16(ch + go, &B[buf][(w * 64 + i * 32) * 16]);
    }
  };
  // stage A (32 rows x 16 k): wave 0 only, 1 load
  auto stageA = [&](int buf, int k0){
    if (w == 0){
      const size_t go = (base + (lane >> 1)) * (size_t)D + k0 * 16 + (lane & 1) * 8;
      GL2LDS16(xh + go, &A[buf][0]);
    }
  };

  f32x16 acc[4];
  #pragma unroll
  for (int s = 0; s < 4; s++)
    #pragma unroll
    for (int j = 0; j < 16; j++) acc[s][j] = 0.f;

  // prologue: A for k0=0, B phases 0 and 1
  stageA(0, 0);
  stageB(0, 0, 0);
  stageB(1, 0, 1);

  bf16x8 a;
  for (int p = 0; p < 32; p++){
    const int k0 = p >> 1, q = p & 1;
    __syncthreads();                 // phase-p slice landed (vmcnt drain); buf[(p+1)&1] free
    const int pn = p + 1;
    if (pn < 32) stageB(pn & 1, pn >> 1, pn & 1);
    if (q == 0){
      if (k0 + 1 < 16) stageA((k0 + 1) & 1, k0 + 1);
      a = *(const bf16x8*)&A[k0 & 1][col * 16 + hi * 8];
    }
    #pragma unroll
    for (int i = 0; i < 2; i++){
      const int s = q * 2 + i;       // sub-tile: codes s*256 + w*32 + col
      const bf16x8 b = *(const bf16x8*)&B[p & 1][(i * 256 + w * 32 + col) * 16 + hi * 8];
      acc[s] = __builtin_amdgcn_mfma_f32_32x32x16_bf16(a, b, acc[s], 0, 0, 0);
    }
  }

  // ---- epilogue: sim -> dist -> iv in place; per-row {max iv, sum iv^2} ----
  float cn[4];
  #pragma unroll
  for (int s = 0; s < 4; s++) cn[s] = cnorm[s * 256 + w * 32 + col];

  float pmax[16], psum[16];
  #pragma unroll
  for (int r = 0; r < 16; r++){
    const int row = (r & 3) + 8 * (r >> 2) + 4 * hi;   // m74/m101-verified 32x32 C layout
    const float xn = xns[row];
    float mx = 0.f, sm = 0.f;
    #pragma unroll
    for (int s = 0; s < 4; s++){
      const float d = xn + cn[s] - 2.0f * acc[s][r];
      const float iv = 1.0f / d;
      acc[s][r] = iv;
      mx = fmaxf(mx, iv);
      sm += iv * iv;
    }
    pmax[r] = mx; psum[r] = sm;
  }
  #pragma unroll
  for (int mask = 1; mask <= 16; mask <<= 1)
    #pragma unroll
    for (int r = 0; r < 16; r++){
      pmax[r] = fmaxf(pmax[r], __shfl_xor(pmax[r], mask));
      psum[r] += __shfl_xor(psum[r], mask);
    }
  if (col == 0){
    #pragma unroll
    for (int r = 0; r < 16; r++){
      const int row = (r & 3) + 8 * (r >> 2) + 4 * hi;
      redmax[w][row] = pmax[r];
      redsum[w][row] = psum[r];
    }
  }
  __syncthreads();
  if (t < 32){
    float mx = 0.f, sm = 0.f;
    #pragma unroll
    for (int ww = 0; ww < 8; ww++){
      mx = fmaxf(mx, redmax[ww][t]);
      sm += redsum[ww][t];
    }
    rowilim[t] = 1.0f / (1.0f / mx + MARGIN);   // iv >= ilim  <=>  d <= dmin + MARGIN
    rowrs[t]   = 1.0f / sm;
  }
  __syncthreads();

  // ---- write soft directly (nt stores) + collect candidates ----
  #pragma unroll
  for (int r = 0; r < 16; r++){
    const int row = (r & 3) + 8 * (r >> 2) + 4 * hi;
    const float ilim = rowilim[row], rs = rowrs[row];
    const size_t rowoff = (base + row) * (size_t)K + w * 32 + col;
    #pragma unroll
    for (int s = 0; s < 4; s++){
      const float iv = acc[s][r];
      __builtin_nontemporal_store(iv * iv * rs, &soft[rowoff + s * 256]);
      if (iv >= ilim){
        const int p = atomicAdd(&lcnt, 1);
        if (p < CAND_MAX) lcand[p] = (row << 10) | (s * 256 + w * 32 + col);
      }
    }
  }
  __syncthreads();
  const int n = min(lcnt, CAND_MAX);
  if (t == 0) cand_cnt[blockIdx.x] = n;
  for (int i = t; i < n; i += 512)
    cand_buf[(size_t)blockIdx.x * CAND_MAX + i] = lcand[i];
}

// ---------------- pass 2: fp64-refined argmin among candidates + quantize + loss ------------
__global__ __launch_bounds__(256) void vq_refine(
    const float* __restrict__ x, const float* __restrict__ cT,
    const int* __restrict__ cand_cnt, const int* __restrict__ cand_buf,
    float* __restrict__ q_out, double* __restrict__ loss_acc)
{
  __shared__ int    lcand[CAND_MAX];
  __shared__ double cand_d[CAND_MAX];
  __shared__ int    rowbest[32];
  __shared__ double bestd[32];

  const int t = threadIdx.x, w = t >> 6, lane = t & 63;
  const size_t base = (size_t)blockIdx.x * 32;
  const int n = cand_cnt[blockIdx.x];
  for (int i = t; i < n; i += 256)
    lcand[i] = cand_buf[(size_t)blockIdx.x * CAND_MAX + i];
  __syncthreads();

  for (int c = w; c < n; c += 4){
    const int rk = lcand[c], r = rk >> 10, k = rk & 1023;
    const float4 xv = *(const float4*)(x  + (base + r) * (size_t)D + lane * 4);
    const float4 cv = *(const float4*)(cT + (size_t)k * D + lane * 4);
    double s = 0.0, dx;
    dx = (double)xv.x - (double)cv.x; s += dx * dx;
    dx = (double)xv.y - (double)cv.y; s += dx * dx;
    dx = (double)xv.z - (double)cv.z; s += dx * dx;
    dx = (double)xv.w - (double)cv.w; s += dx * dx;
    s = wave_sum_d(s);
    if (lane == 0) cand_d[c] = s;
  }
  __syncthreads();

  if (t < 32){
    double best = 1e300; int bi = 1 << 20;
    for (int c = 0; c < n; c++){
      const int rk = lcand[c];
      if ((rk >> 10) == t){
        const double dd = cand_d[c];
        const int k = rk & 1023;
        if (dd < best || (dd == best && k < bi)){ best = dd; bi = k; }
      }
    }
    rowbest[t] = (bi < K) ? bi : 0;   // OOB safety; impossible in practice
    bestd[t] = best;
  }
  __syncthreads();

  #pragma unroll 4
  for (int r = 0; r < 32; r++){
    const float q = cT[(size_t)rowbest[r] * D + t];
    __builtin_nontemporal_store(q, &q_out[(base + r) * (size_t)D + t]);
  }

  if (t == 0){
    double s = 0.0;
    #pragma unroll
    for (int r = 0; r < 32; r++) s += bestd[r];
    atomicAdd(loss_acc, s);
  }
}

// ---------------- finalize loss ----------------
__global__ void finalize_loss(const double* __restrict__ acc, float* __restrict__ out_loss){
  out_loss[0] = (float)(1.25 * acc[0] / (double)((size_t)NROWS * D));
}

extern "C" void kernel_launch(void* const* d_in, const int* in_sizes, int n_in,
                              void* d_out, int out_size, void* d_ws, size_t ws_size,
                              hipStream_t stream) {
  const float* x  = (const float*)d_in[0];   // [65536,256]
  const float* cb = (const float*)d_in[1];   // [256,1024]

  float* out      = (float*)d_out;
  float* q_out    = out;                                          // 16777216
  float* soft     = out + (size_t)NROWS * D;                      // 67108864
  float* loss_out = out + (size_t)NROWS * D + (size_t)NROWS * K;  // 1

  char* ws = (char*)d_ws;
  double* acc      = (double*)ws;                 // @0        (8 B)
  float*  cnorm    = (float*)(ws + 4096);         // 4 KB
  int*    cand_cnt = (int*)(ws + 16384);          // 8 KB
  float*  xnorm    = (float*)(ws + 262144);       // 256 KB
  int*    cand_buf = (int*)(ws + 524288);         // 4 MB (2048 blocks x 512 x 4B)
  float*  cT       = (float*)(ws + 4718592);      // 1 MB
  __bf16* ch       = (__bf16*)(ws + 5767168);     // 512 KB
  __bf16* xh       = (__bf16*)(ws + 6291456);     // 32 MB  (total ~38.5 MB)

  hipMemsetAsync(acc, 0, sizeof(double), stream);
  split_rows<<<NROWS / 4, 256, 0, stream>>>(x, xh, xnorm);
  prep_codebook<<<K, 256, 0, stream>>>(cb, cT, ch, cnorm);
  vq_fused<<<NROWS / 32, 512, 0, stream>>>(xh, ch, cnorm, xnorm, soft, cand_cnt, cand_buf);
  vq_refine<<<NROWS / 32, 256, 0, stream>>>(x, cT, cand_cnt, cand_buf, q_out, acc);
  finalize_loss<<<1, 1, 0, stream>>>(acc, loss_out);
}

// Round 7
// 551.394 us; speedup vs baseline: 1.2680x; 1.0415x over previous
//
#include <hip/hip_runtime.h>
#include <math.h>

#define D 256
#define K 1024
#define NROWS 65536
#define MARGIN 0.75f
#define CAND_MAX 512

typedef __bf16 bf16x8 __attribute__((ext_vector_type(8)));
typedef float f32x16 __attribute__((ext_vector_type(16)));

// async global->LDS, 16B per lane; lds base must be wave-uniform, lane i lands at base + i*16
#define GL2LDS16(g, l) __builtin_amdgcn_global_load_lds( \
    (const __attribute__((address_space(1))) char*)(const void*)(g), \
    (__attribute__((address_space(3))) char*)(void*)(l), 16, 0, 0)

// counted vmcnt wait (T4): literal immediate, memory clobber orders surrounding mem ops
#define WAITV(N) asm volatile("s_waitcnt vmcnt(" #N ")" ::: "memory")

__device__ inline float wave_sum_f(float v){
  #pragma unroll
  for (int off = 32; off; off >>= 1) v += __shfl_down(v, off);
  return v;
}
__device__ inline double wave_sum_d(double v){
  #pragma unroll
  for (int off = 32; off; off >>= 1) v += __shfl_down(v, off);
  return v;
}

// ---------------- pass 0a: x -> bf16 + fp32 row norms ----------------
__global__ __launch_bounds__(256) void split_rows(const float* __restrict__ x,
                                                  __bf16* __restrict__ xh,
                                                  float* __restrict__ xnorm){
  const int t = threadIdx.x;
  const int w = t >> 6, lane = t & 63;
  const size_t row = (size_t)blockIdx.x * 4 + w;
  const float4 v = *(const float4*)(x + row * D + lane * 4);
  float s = v.x*v.x + v.y*v.y + v.z*v.z + v.w*v.w;
  s = wave_sum_f(s);
  union { __bf16 b[4]; short4 s4; } uh;
  uh.b[0] = (__bf16)v.x; uh.b[1] = (__bf16)v.y;
  uh.b[2] = (__bf16)v.z; uh.b[3] = (__bf16)v.w;
  *(short4*)(xh + row * D + lane * 4) = uh.s4;
  if (lane == 0) xnorm[row] = s;
}

// ---------------- pass 0b: codebook transpose (fp32 + bf16) + fp32 col norms ----------------
__global__ __launch_bounds__(256) void prep_codebook(const float* __restrict__ cb,
                                                     float* __restrict__ cT,
                                                     __bf16* __restrict__ ch,
                                                     float* __restrict__ cnorm){
  const int k = blockIdx.x;
  const int t = threadIdx.x;
  const int w = t >> 6, lane = t & 63;
  float v = cb[(size_t)t * K + k];
  cT[(size_t)k * D + t] = v;
  ch[(size_t)k * D + t] = (__bf16)v;
  float s = wave_sum_f(v * v);
  __shared__ float red[4];
  if (lane == 0) red[w] = s;
  __syncthreads();
  if (t == 0) cnorm[k] = red[0] + red[1] + red[2] + red[3];
}

// ---------------- fused pass 1: 32-row x 1024-code block, counted-vmcnt 4-deep pipeline ------
// 512 threads = 8 waves, 2 blocks/CU. 32 phases; phase p consumes B-ring slot p&3 (512 codes x
// 16 k, staged 3 phases ahead) and does 2 MFMAs/wave. Raw s_barrier + per-wave counted vmcnt:
//   waves 1-7: N=4 (p<=29), 2 (p=30), 0 (p=31)
//   wave 0 (also stages A one k0 ahead): p=0 ->4; even p -> 2 (A in FIFO), p=30 -> 0; odd -> 5.
// Barrier AFTER the wait makes per-wave load confirmations collective. stageB(p+3) overwrites
// ring slot (p-1)&3 whose reads completed before barrier p (MFMA lgkmcnt dependency).
__global__ __launch_bounds__(512, 4) void vq_fused(
    const __bf16* __restrict__ xh, const __bf16* __restrict__ ch,
    const float* __restrict__ cnorm, const float* __restrict__ xnorm,
    float* __restrict__ soft, int* __restrict__ cand_cnt, int* __restrict__ cand_buf)
{
  __shared__ __bf16 B[4][512 * 16];    // 16 KB each -> 64 KB ring
  __shared__ __bf16 A[2][32 * 16];     // 1 KB each
  __shared__ float xns[32];
  __shared__ float rowilim[32];
  __shared__ float rowrs[32];
  __shared__ int   lcnt;
  // post-loop overlays on B (all MFMA reads drained by then):
  float* redmax = (float*)&B[0][0];          // [8][32]
  float* redsum = redmax + 256;              // [8][32]
  int*   lcand  = (int*)(redsum + 256);      // [CAND_MAX]

  const int t = threadIdx.x, w = t >> 6, lane = t & 63;
  const int col = lane & 31, hi = lane >> 5;
  const size_t base = (size_t)blockIdx.x * 32;

  if (t < 32) xns[t] = xnorm[base + t];
  if (t == 0) lcnt = 0;
  __syncthreads();   // xns/lcnt visible; also before first LDS DMA targeting B

  // stage one 512-code x 16-k slice (phase index p -> k0=p>>1, q=p&1): 2 loads per wave
  auto stageB = [&](int buf, int k0, int q){
    #pragma unroll
    for (int i = 0; i < 2; i++){
      const size_t go = (size_t)(q * 512 + w * 64 + i * 32 + (lane >> 1)) * D
                        + k0 * 16 + (lane & 1) * 8;
      GL2LDS16(ch + go, &B[buf][(w * 64 + i * 32) * 16]);
    }
  };
  // stage A (32 rows x 16 k): wave 0 only, 1 load
  auto stageA = [&](int buf, int k0){
    if (w == 0){
      const size_t go = (base + (lane >> 1)) * (size_t)D + k0 * 16 + (lane & 1) * 8;
      GL2LDS16(xh + go, &A[buf][0]);
    }
  };

  f32x16 acc[4];
  #pragma unroll
  for (int s = 0; s < 4; s++)
    #pragma unroll
    for (int j = 0; j < 16; j++) acc[s][j] = 0.f;

  // prologue: A(0); B phases 0,1,2  (FIFO per wave: [A0,] B0,B0, B1,B1, B2,B2)
  stageA(0, 0);
  stageB(0, 0, 0);
  stageB(1, 0, 1);
  stageB(2, 1, 0);

  for (int k0 = 0; k0 < 16; k0++){
    const int p = 2 * k0;

    // ---- even phase p (q=0): consume B[p&3] + A[k0&1]; sub-tiles 0,1 ----
    if (w == 0){
      if (p == 0)       WAITV(4);
      else if (p == 30) WAITV(0);
      else              WAITV(2);
    } else {
      if (p <= 29)      WAITV(4);
      else if (p == 30) WAITV(2);
      else              WAITV(0);
    }
    __builtin_amdgcn_s_barrier();
    {
      const int pn = p + 3;
      if (pn <= 31) stageB(pn & 3, pn >> 1, pn & 1);
    }
    if (k0 + 1 < 16) stageA((k0 + 1) & 1, k0 + 1);   // wave 0 internally
    const bf16x8 a = *(const bf16x8*)&A[k0 & 1][col * 16 + hi * 8];
    #pragma unroll
    for (int i = 0; i < 2; i++){
      const bf16x8 b = *(const bf16x8*)&B[p & 3][(i * 256 + w * 32 + col) * 16 + hi * 8];
      acc[i] = __builtin_amdgcn_mfma_f32_32x32x16_bf16(a, b, acc[i], 0, 0, 0);
    }

    // ---- odd phase p+1 (q=1): consume B[(p+1)&3]; sub-tiles 2,3 (a reused) ----
    const int p1 = p + 1;
    if (w == 0){
      if (p1 <= 29) WAITV(5);
      else          WAITV(0);
    } else {
      if (p1 <= 29)      WAITV(4);
      else if (p1 == 30) WAITV(2);
      else               WAITV(0);
    }
    __builtin_amdgcn_s_barrier();
    {
      const int pn = p1 + 3;
      if (pn <= 31) stageB(pn & 3, pn >> 1, pn & 1);
    }
    #pragma unroll
    for (int i = 0; i < 2; i++){
      const bf16x8 b = *(const bf16x8*)&B[p1 & 3][(i * 256 + w * 32 + col) * 16 + hi * 8];
      acc[2 + i] = __builtin_amdgcn_mfma_f32_32x32x16_bf16(a, b, acc[2 + i], 0, 0, 0);
    }
  }

  // ---- epilogue: sim -> dist -> iv in place; per-row {max iv, sum iv^2} ----
  __syncthreads();   // all vmcnt==0 (p=31 wait); safe to overlay scratch onto B

  float cn[4];
  #pragma unroll
  for (int s = 0; s < 4; s++) cn[s] = cnorm[s * 256 + w * 32 + col];

  float pmax[16], psum[16];
  #pragma unroll
  for (int r = 0; r < 16; r++){
    const int row = (r & 3) + 8 * (r >> 2) + 4 * hi;   // m74/m101-verified 32x32 C layout
    const float xn = xns[row];
    float mx = 0.f, sm = 0.f;
    #pragma unroll
    for (int s = 0; s < 4; s++){
      const float d = xn + cn[s] - 2.0f * acc[s][r];
      const float iv = 1.0f / d;
      acc[s][r] = iv;
      mx = fmaxf(mx, iv);
      sm += iv * iv;
    }
    pmax[r] = mx; psum[r] = sm;
  }
  #pragma unroll
  for (int mask = 1; mask <= 16; mask <<= 1)
    #pragma unroll
    for (int r = 0; r < 16; r++){
      pmax[r] = fmaxf(pmax[r], __shfl_xor(pmax[r], mask));
      psum[r] += __shfl_xor(psum[r], mask);
    }
  if (col == 0){
    #pragma unroll
    for (int r = 0; r < 16; r++){
      const int row = (r & 3) + 8 * (r >> 2) + 4 * hi;
      redmax[w * 32 + row] = pmax[r];
      redsum[w * 32 + row] = psum[r];
    }
  }
  __syncthreads();
  if (t < 32){
    float mx = 0.f, sm = 0.f;
    #pragma unroll
    for (int ww = 0; ww < 8; ww++){
      mx = fmaxf(mx, redmax[ww * 32 + t]);
      sm += redsum[ww * 32 + t];
    }
    rowilim[t] = 1.0f / (1.0f / mx + MARGIN);   // iv >= ilim  <=>  d <= dmin + MARGIN
    rowrs[t]   = 1.0f / sm;
  }
  __syncthreads();

  // ---- write soft directly (nt stores) + collect candidates ----
  #pragma unroll
  for (int r = 0; r < 16; r++){
    const int row = (r & 3) + 8 * (r >> 2) + 4 * hi;
    const float ilim = rowilim[row], rs = rowrs[row];
    const size_t rowoff = (base + row) * (size_t)K + w * 32 + col;
    #pragma unroll
    for (int s = 0; s < 4; s++){
      const float iv = acc[s][r];
      __builtin_nontemporal_store(iv * iv * rs, &soft[rowoff + s * 256]);
      if (iv >= ilim){
        const int pc = atomicAdd(&lcnt, 1);
        if (pc < CAND_MAX) lcand[pc] = (row << 10) | (s * 256 + w * 32 + col);
      }
    }
  }
  __syncthreads();
  const int n = min(lcnt, CAND_MAX);
  if (t == 0) cand_cnt[blockIdx.x] = n;
  for (int i = t; i < n; i += 512)
    cand_buf[(size_t)blockIdx.x * CAND_MAX + i] = lcand[i];
}

// ---------------- pass 2: fp64-refined argmin among candidates + quantize + loss ------------
__global__ __launch_bounds__(256) void vq_refine(
    const float* __restrict__ x, const float* __restrict__ cT,
    const int* __restrict__ cand_cnt, const int* __restrict__ cand_buf,
    float* __restrict__ q_out, double* __restrict__ loss_acc)
{
  __shared__ int    lcand[CAND_MAX];
  __shared__ double cand_d[CAND_MAX];
  __shared__ int    rowbest[32];
  __shared__ double bestd[32];

  const int t = threadIdx.x, w = t >> 6, lane = t & 63;
  const size_t base = (size_t)blockIdx.x * 32;
  const int n = cand_cnt[blockIdx.x];
  for (int i = t; i < n; i += 256)
    lcand[i] = cand_buf[(size_t)blockIdx.x * CAND_MAX + i];
  __syncthreads();

  for (int c = w; c < n; c += 4){
    const int rk = lcand[c], r = rk >> 10, k = rk & 1023;
    const float4 xv = *(const float4*)(x  + (base + r) * (size_t)D + lane * 4);
    const float4 cv = *(const float4*)(cT + (size_t)k * D + lane * 4);
    double s = 0.0, dx;
    dx = (double)xv.x - (double)cv.x; s += dx * dx;
    dx = (double)xv.y - (double)cv.y; s += dx * dx;
    dx = (double)xv.z - (double)cv.z; s += dx * dx;
    dx = (double)xv.w - (double)cv.w; s += dx * dx;
    s = wave_sum_d(s);
    if (lane == 0) cand_d[c] = s;
  }
  __syncthreads();

  if (t < 32){
    double best = 1e300; int bi = 1 << 20;
    for (int c = 0; c < n; c++){
      const int rk = lcand[c];
      if ((rk >> 10) == t){
        const double dd = cand_d[c];
        const int k = rk & 1023;
        if (dd < best || (dd == best && k < bi)){ best = dd; bi = k; }
      }
    }
    rowbest[t] = (bi < K) ? bi : 0;   // OOB safety; impossible in practice
    bestd[t] = best;
  }
  __syncthreads();

  #pragma unroll 4
  for (int r = 0; r < 32; r++){
    const float q = cT[(size_t)rowbest[r] * D + t];
    __builtin_nontemporal_store(q, &q_out[(base + r) * (size_t)D + t]);
  }

  if (t == 0){
    double s = 0.0;
    #pragma unroll
    for (int r = 0; r < 32; r++) s += bestd[r];
    atomicAdd(loss_acc, s);
  }
}

// ---------------- finalize loss ----------------
__global__ void finalize_loss(const double* __restrict__ acc, float* __restrict__ out_loss){
  out_loss[0] = (float)(1.25 * acc[0] / (double)((size_t)NROWS * D));
}

extern "C" void kernel_launch(void* const* d_in, const int* in_sizes, int n_in,
                              void* d_out, int out_size, void* d_ws, size_t ws_size,
                              hipStream_t stream) {
  const float* x  = (const float*)d_in[0];   // [65536,256]
  const float* cb = (const float*)d_in[1];   // [256,1024]

  float* out      = (float*)d_out;
  float* q_out    = out;                                          // 16777216
  float* soft     = out + (size_t)NROWS * D;                      // 67108864
  float* loss_out = out + (size_t)NROWS * D + (size_t)NROWS * K;  // 1

  char* ws = (char*)d_ws;
  double* acc      = (double*)ws;                 // @0        (8 B)
  float*  cnorm    = (float*)(ws + 4096);         // 4 KB
  int*    cand_cnt = (int*)(ws + 16384);          // 8 KB
  float*  xnorm    = (float*)(ws + 262144);       // 256 KB
  int*    cand_buf = (int*)(ws + 524288);         // 4 MB (2048 blocks x 512 x 4B)
  float*  cT       = (float*)(ws + 4718592);      // 1 MB
  __bf16* ch       = (__bf16*)(ws + 5767168);     // 512 KB
  __bf16* xh       = (__bf16*)(ws + 6291456);     // 32 MB  (total ~38.5 MB)

  hipMemsetAsync(acc, 0, sizeof(double), stream);
  split_rows<<<NROWS / 4, 256, 0, stream>>>(x, xh, xnorm);
  prep_codebook<<<K, 256, 0, stream>>>(cb, cT, ch, cnorm);
  vq_fused<<<NROWS / 32, 512, 0, stream>>>(xh, ch, cnorm, xnorm, soft, cand_cnt, cand_buf);
  vq_refine<<<NROWS / 32, 256, 0, stream>>>(x, cT, cand_cnt, cand_buf, q_out, acc);
  finalize_loss<<<1, 1, 0, stream>>>(acc, loss_out);
}